// Round 4
// baseline (754.501 us; speedup 1.0000x reference)
//
#include <hip/hip_runtime.h>
#include <hip/hip_bf16.h>

// BiAttention: B=16, L=M=2048, D=1024.
//  conv -> tr -> gemm1(S=QK^T+dots,mask) -> softmax_rows -> w2a -> o2 -> gemm2(fused epilogue)
// R4: GEMMs use a fine-phase counted-vmcnt pipeline (T3+T4):
//  - K split into 32-half slices; LDS ring of 4 slices per matrix (128 KB).
//  - per phase: stage slice h+3 (4 GL16) -> 12 ds_read_b128 + 32 MFMA (T5 setprio)
//    -> vmcnt(8) (2 slice-groups in flight, never drain mid-loop) -> s_barrier.
//  - LDS chunk swizzle slot=(c+row>>1)&3 => perfect 2-way bank access (free).
//    GL16 dest linear; global source chunk inverse-permuted (rule 21).

#define BDIM 16
#define LDIM 2048
#define MDIM 2048
#define DDIM 1024
#define NEGF (-60000.0f)
#define SLOT 8192   // halfs per ring slot: 256 rows * 32 halfs

typedef float    f32x4v __attribute__((ext_vector_type(4)));
typedef _Float16 half8  __attribute__((ext_vector_type(8)));
typedef _Float16 half4  __attribute__((ext_vector_type(4)));

#define GL16(gp, lp)                                                        \
  __builtin_amdgcn_global_load_lds(                                         \
      (const __attribute__((address_space(1))) unsigned int*)(gp),          \
      (__attribute__((address_space(3))) unsigned int*)(lp), 16, 0, 0)

// ---------------- conversion + row dots ----------------
__global__ __launch_bounds__(256) void conv_kernel(
    const float* __restrict__ input, const float* __restrict__ memory,
    const float* __restrict__ w_in, const float* __restrict__ w_mem,
    const float* __restrict__ scale,
    _Float16* __restrict__ Qh, _Float16* __restrict__ Kh,
    float* __restrict__ idot, float* __restrict__ mdot) {
  const int t = threadIdx.x, lane = t & 63, wid = t >> 6;
  const size_t row = (size_t)blockIdx.x * 4 + wid;
  const float* ir  = input  + row * DDIM;
  const float* mrp = memory + row * DDIM;
  float di = 0.f, dm = 0.f;
#pragma unroll
  for (int c = 0; c < 4; ++c) {
    const int off = c * 256 + lane * 4;
    float4 sc4 = *(const float4*)&scale[off];
    float4 wi4 = *(const float4*)&w_in[off];
    float4 wm4 = *(const float4*)&w_mem[off];
    float4 v = *(const float4*)&ir[off];
    di += v.x * wi4.x + v.y * wi4.y + v.z * wi4.z + v.w * wi4.w;
    half4 q = { (_Float16)(v.x * sc4.x), (_Float16)(v.y * sc4.y),
                (_Float16)(v.z * sc4.z), (_Float16)(v.w * sc4.w) };
    *(half4*)&Qh[row * DDIM + off] = q;
    float4 u = *(const float4*)&mrp[off];
    dm += u.x * wm4.x + u.y * wm4.y + u.z * wm4.z + u.w * wm4.w;
    half4 k = { (_Float16)u.x, (_Float16)u.y, (_Float16)u.z, (_Float16)u.w };
    *(half4*)&Kh[row * DDIM + off] = k;
  }
#pragma unroll
  for (int o = 1; o < 64; o <<= 1) {
    di += __shfl_xor(di, o, 64);
    dm += __shfl_xor(dm, o, 64);
  }
  if (lane == 0) { idot[row] = di; mdot[row] = dm; }
}

// ---------------- transpose memory (f16) -> Vt[b][d][m] ----------------
__global__ __launch_bounds__(256) void tr_kernel(const _Float16* __restrict__ Kh,
                                                 _Float16* __restrict__ Vt) {
  const int b = blockIdx.z;
  const int d0 = blockIdx.x * 64, m0 = blockIdx.y * 64;
  __shared__ _Float16 sT[64][80];
  const int t = threadIdx.x;
  {
    const int mr = t >> 2, ch = (t & 3) * 16;
    const _Float16* src = Kh + ((size_t)b * MDIM + m0 + mr) * DDIM + d0 + ch;
    *(half8*)&sT[mr][ch]     = *(const half8*)&src[0];
    *(half8*)&sT[mr][ch + 8] = *(const half8*)&src[8];
  }
  __syncthreads();
  {
    const int dr = t >> 2, mc = (t & 3) * 16;
    union { _Float16 h[16]; half8 v[2]; } tmp;
#pragma unroll
    for (int j = 0; j < 16; ++j) tmp.h[j] = sT[mc + j][dr];
    _Float16* dst = Vt + ((size_t)b * DDIM + d0 + dr) * MDIM + m0 + mc;
    *(half8*)&dst[0] = tmp.v[0];
    *(half8*)&dst[8] = tmp.v[1];
  }
}

// ============ fine-phase GEMM core ============
// stage one 256x32 K-slice of A and B into ring slots (linear GL16 dest,
// inverse-permuted global source chunk: LDS slot col = (c + row>>1)&3).
__device__ __forceinline__ void stage_half(const _Float16* __restrict__ Ab,
                                           const _Float16* __restrict__ Bb,
                                           _Float16* sAslot, _Float16* sBslot,
                                           int stride, int k0, int wid, int lane) {
  const int r0  = wid * 32;
  const int sub = lane >> 2;     // 0..15 row within 16-row chunk
  const int q   = lane & 3;      // LDS slot col
#pragma unroll
  for (int gl = 0; gl < 2; ++gl) {
    const int rl = r0 + gl * 16 + sub;          // local row 0..255
    const int c  = (q - (rl >> 1)) & 3;         // source k-chunk
    const size_t go = (size_t)rl * stride + k0 + c * 8;
    GL16(Ab + go, sAslot + (r0 + gl * 16) * 32);
    GL16(Bb + go, sBslot + (r0 + gl * 16) * 32);
  }
}

// one phase: 12 ds_read_b128 + 32 MFMA on ring slot (setprio-wrapped)
__device__ __forceinline__ void compute_phase(const _Float16* sAslot,
                                              const _Float16* sBslot,
                                              f32x4v acc[8][4], int wrow, int wcol,
                                              int lane) {
  const int l15 = lane & 15, cc = lane >> 4;
  half8 bF[4];
#pragma unroll
  for (int n = 0; n < 4; ++n) {
    const int row = wcol * 64 + n * 16 + l15;
    bF[n] = *(const half8*)&sBslot[row * 32 + (((cc + (row >> 1)) & 3) << 3)];
  }
  half8 aF[8];
#pragma unroll
  for (int m = 0; m < 8; ++m) {
    const int row = wrow * 128 + m * 16 + l15;
    aF[m] = *(const half8*)&sAslot[row * 32 + (((cc + (row >> 1)) & 3) << 3)];
  }
  __builtin_amdgcn_s_setprio(1);
#pragma unroll
  for (int m = 0; m < 8; ++m)
#pragma unroll
    for (int n = 0; n < 4; ++n)
      acc[m][n] = __builtin_amdgcn_mfma_f32_16x16x32_f16(aF[m], bF[n], acc[m][n], 0, 0, 0);
  __builtin_amdgcn_s_setprio(0);
}

// the K-loop pipeline shared by both GEMMs
#define GEMM_PIPELINE(Ab, Bb, stride, H)                                        \
  stage_half(Ab, Bb, sA, sB, stride, 0, wid, lane);                             \
  stage_half(Ab, Bb, sA + SLOT, sB + SLOT, stride, 32, wid, lane);              \
  stage_half(Ab, Bb, sA + 2 * SLOT, sB + 2 * SLOT, stride, 64, wid, lane);      \
  asm volatile("s_waitcnt vmcnt(8)" ::: "memory");                              \
  __builtin_amdgcn_s_barrier();                                                 \
  __builtin_amdgcn_sched_barrier(0);                                            \
  for (int h = 0; h < (H); ++h) {                                               \
    if (h + 3 < (H)) {                                                          \
      const int ss = (h + 3) & 3;                                               \
      stage_half(Ab, Bb, sA + ss * SLOT, sB + ss * SLOT, stride,                \
                 (h + 3) * 32, wid, lane);                                      \
    }                                                                           \
    const int sl = h & 3;                                                       \
    compute_phase(sA + sl * SLOT, sB + sl * SLOT, acc, wrow, wcol, lane);       \
    if (h < (H) - 3)       asm volatile("s_waitcnt vmcnt(8)" ::: "memory");     \
    else if (h == (H) - 3) asm volatile("s_waitcnt vmcnt(4)" ::: "memory");     \
    else if (h == (H) - 2) asm volatile("s_waitcnt vmcnt(0)" ::: "memory");     \
    __builtin_amdgcn_s_barrier();                                               \
    __builtin_amdgcn_sched_barrier(0);                                          \
  }

// ---------------- GEMM1: S = Q @ K^T + dots, masked ----------------
__global__ __launch_bounds__(512, 2) void gemm1_kernel(
    const _Float16* __restrict__ Qh, const _Float16* __restrict__ Kh,
    const float* __restrict__ idot, const float* __restrict__ mdot,
    const int* __restrict__ mask, _Float16* __restrict__ Sp) {
  const int id = blockIdx.x;                 // nwg = 1024
  const int wg = (id & 7) * 128 + (id >> 3);
  const int b = wg >> 6, rem = wg & 63, by = rem >> 3, bx = rem & 7;
  const int t = threadIdx.x, lane = t & 63, wid = t >> 6;
  const int wrow = wid >> 2, wcol = wid & 3;
  __shared__ _Float16 sA[4 * SLOT];
  __shared__ _Float16 sB[4 * SLOT];
  __shared__ float s_dl[256], s_dm[256];
  __shared__ int   s_ml[256], s_mm[256];
  if (t < 256) {
    s_dl[t] = idot[b * LDIM + by * 256 + t];
    s_ml[t] = mask[b * LDIM + by * 256 + t];
    s_dm[t] = mdot[b * MDIM + bx * 256 + t];
    s_mm[t] = mask[b * MDIM + bx * 256 + t];
  }
  const _Float16* Ab = Qh + ((size_t)b * LDIM + by * 256) * DDIM;
  const _Float16* Bb = Kh + ((size_t)b * MDIM + bx * 256) * DDIM;
  f32x4v acc[8][4];
#pragma unroll
  for (int i = 0; i < 8; ++i)
#pragma unroll
    for (int j = 0; j < 4; ++j) acc[i][j] = (f32x4v){0.f, 0.f, 0.f, 0.f};

  GEMM_PIPELINE(Ab, Bb, DDIM, DDIM / 32)

  const int rb = wrow * 128, cb = wcol * 64;
#pragma unroll
  for (int mi = 0; mi < 8; ++mi)
#pragma unroll
    for (int ni = 0; ni < 4; ++ni)
#pragma unroll
      for (int r = 0; r < 4; ++r) {
        const int lrow = rb + mi * 16 + (lane >> 4) * 4 + r;
        const int lcol = cb + ni * 16 + (lane & 15);
        float s = acc[mi][ni][r] + s_dl[lrow] + s_dm[lcol];
        if ((s_ml[lrow] | s_mm[lcol]) != 0) s = NEGF;
        Sp[((size_t)b * LDIM + by * 256 + lrow) * MDIM + bx * 256 + lcol] = (_Float16)s;
      }
}

// ---------------- per-row softmax (in place) + rowmax ----------------
__global__ __launch_bounds__(256) void softmax_rows(_Float16* __restrict__ Sp,
                                                    float* __restrict__ rmax) {
  const int t = threadIdx.x, lane = t & 63, wid = t >> 6;
  const size_t row = (size_t)blockIdx.x * 4 + wid;
  _Float16* rp = Sp + row * (size_t)MDIM;
  float s[32];
#pragma unroll
  for (int c = 0; c < 4; ++c) {
    half8 v = *(const half8*)&rp[c * 512 + lane * 8];
#pragma unroll
    for (int j = 0; j < 8; ++j) s[c * 8 + j] = (float)v[j];
  }
  float m = -3.0e38f;
#pragma unroll
  for (int i = 0; i < 32; ++i) m = fmaxf(m, s[i]);
#pragma unroll
  for (int o = 1; o < 64; o <<= 1) m = fmaxf(m, __shfl_xor(m, o, 64));
  float sum = 0.f;
#pragma unroll
  for (int i = 0; i < 32; ++i) { s[i] = __expf(s[i] - m); sum += s[i]; }
#pragma unroll
  for (int o = 1; o < 64; o <<= 1) sum += __shfl_xor(sum, o, 64);
  const float inv = 1.f / sum;
#pragma unroll
  for (int c = 0; c < 4; ++c) {
    half8 v;
#pragma unroll
    for (int j = 0; j < 8; ++j) v[j] = (_Float16)(s[c * 8 + j] * inv);
    *(half8*)&rp[c * 512 + lane * 8] = v;
  }
  if (lane == 0) rmax[row] = m;
}

// ---------------- w2 = softmax_l(rowmax) per batch ----------------
__global__ __launch_bounds__(256) void w2a_kernel(const float* __restrict__ rmax,
                                                  float* __restrict__ w2) {
  const int b = blockIdx.x, t = threadIdx.x;
  __shared__ float red[256];
  const float* rm = rmax + (size_t)b * LDIM;
  float vals[8]; float lm = -3.0e38f;
#pragma unroll
  for (int j = 0; j < 8; ++j) { vals[j] = rm[t + j * 256]; lm = fmaxf(lm, vals[j]); }
  red[t] = lm; __syncthreads();
  for (int s = 128; s > 0; s >>= 1) {
    if (t < s) red[t] = fmaxf(red[t], red[t + s]);
    __syncthreads();
  }
  const float M = red[0]; __syncthreads();
  float ls = 0.f;
#pragma unroll
  for (int j = 0; j < 8; ++j) ls += __expf(vals[j] - M);
  red[t] = ls; __syncthreads();
  for (int s = 128; s > 0; s >>= 1) {
    if (t < s) red[t] += red[t + s];
    __syncthreads();
  }
  const float inv = 1.f / red[0];
#pragma unroll
  for (int j = 0; j < 8; ++j) w2[(size_t)b * LDIM + t + j * 256] = __expf(vals[j] - M) * inv;
}

// ---------------- o2 ----------------
__global__ void o2init_kernel(float* __restrict__ o2) {
  o2[blockIdx.x * 256 + threadIdx.x] = 0.f;
}

__global__ __launch_bounds__(256) void o2_kernel(const float* __restrict__ input,
                                                 const float* __restrict__ w2,
                                                 float* __restrict__ o2) {
  const int b = blockIdx.y, ch = blockIdx.x, t = threadIdx.x;
  __shared__ float sw[128];
  if (t < 128) sw[t] = w2[(size_t)b * LDIM + ch * 128 + t];
  __syncthreads();
  const float* ib = input + ((size_t)b * LDIM + ch * 128) * DDIM;
  float4 acc = {0.f, 0.f, 0.f, 0.f};
  for (int l = 0; l < 128; ++l) {
    const float w = sw[l];
    float4 v = *(const float4*)&ib[(size_t)l * DDIM + t * 4];
    acc.x += w * v.x; acc.y += w * v.y; acc.z += w * v.z; acc.w += w * v.w;
  }
  atomicAdd(&o2[b * DDIM + t * 4 + 0], acc.x);
  atomicAdd(&o2[b * DDIM + t * 4 + 1], acc.y);
  atomicAdd(&o2[b * DDIM + t * 4 + 2], acc.z);
  atomicAdd(&o2[b * DDIM + t * 4 + 3], acc.w);
}

// ---------------- GEMM2: o1 = P @ V, fused epilogue ----------------
__global__ __launch_bounds__(512, 2) void gemm2_kernel(
    const _Float16* __restrict__ Pm, const _Float16* __restrict__ Vt,
    const float* __restrict__ input, const float* __restrict__ o2,
    float* __restrict__ out) {
  const int id = blockIdx.x;                 // nwg = 512
  const int wg = (id & 7) * 64 + (id >> 3);
  const int b = wg >> 5, rem = wg & 31, by = rem >> 2, bx = rem & 3;
  const int t = threadIdx.x, lane = t & 63, wid = t >> 6;
  const int wrow = wid >> 2, wcol = wid & 3;
  __shared__ _Float16 sA[4 * SLOT];
  __shared__ _Float16 sB[4 * SLOT];
  const _Float16* Ab = Pm + ((size_t)b * LDIM + by * 256) * MDIM;
  const _Float16* Bb = Vt + ((size_t)b * DDIM + bx * 256) * MDIM;
  f32x4v acc[8][4];
#pragma unroll
  for (int i = 0; i < 8; ++i)
#pragma unroll
    for (int j = 0; j < 4; ++j) acc[i][j] = (f32x4v){0.f, 0.f, 0.f, 0.f};

  GEMM_PIPELINE(Ab, Bb, MDIM, MDIM / 32)

  const int rb = wrow * 128, cb = wcol * 64;
#pragma unroll
  for (int mi = 0; mi < 8; ++mi)
#pragma unroll
    for (int ni = 0; ni < 4; ++ni)
#pragma unroll
      for (int r = 0; r < 4; ++r) {
        const int lrow = rb + mi * 16 + (lane >> 4) * 4 + r;
        const int lcol = cb + ni * 16 + (lane & 15);
        const size_t l = (size_t)by * 256 + lrow;
        const int d = bx * 256 + lcol;
        const float o1 = acc[mi][ni][r];
        const float inp = input[((size_t)b * LDIM + l) * DDIM + d];
        const float o2v = o2[b * DDIM + d];
        const size_t ob = ((size_t)b * LDIM + l) * (4 * DDIM) + d;
        out[ob] = inp;
        out[ob + DDIM] = o1;
        out[ob + 2 * DDIM] = inp * o1;
        out[ob + 3 * DDIM] = o2v * o1;
      }
}

extern "C" void kernel_launch(void* const* d_in, const int* in_sizes, int n_in,
                              void* d_out, int out_size, void* d_ws, size_t ws_size,
                              hipStream_t stream) {
  (void)in_sizes; (void)n_in; (void)out_size; (void)ws_size;
  const float* input  = (const float*)d_in[0];
  const float* memory = (const float*)d_in[1];
  const int*   mask   = (const int*)d_in[2];
  const float* w_in   = (const float*)d_in[3];
  const float* w_mem  = (const float*)d_in[4];
  const float* scale  = (const float*)d_in[5];
  float* out = (float*)d_out;

  char* p = (char*)d_ws;
  _Float16* Qh = (_Float16*)p; p += (size_t)BDIM * LDIM * DDIM * 2;
  _Float16* Kh = (_Float16*)p; p += (size_t)BDIM * MDIM * DDIM * 2;
  _Float16* Vt = (_Float16*)p; p += (size_t)BDIM * DDIM * MDIM * 2;
  _Float16* Sp = (_Float16*)p; p += (size_t)BDIM * LDIM * MDIM * 2;
  float* idot = (float*)p; p += (size_t)BDIM * LDIM * 4;
  float* mdot = (float*)p; p += (size_t)BDIM * MDIM * 4;
  float* rmax = (float*)p; p += (size_t)BDIM * LDIM * 4;
  float* w2   = (float*)p; p += (size_t)BDIM * LDIM * 4;
  float* o2   = (float*)p; p += (size_t)BDIM * DDIM * 4;

  conv_kernel<<<dim3(BDIM * LDIM / 4), dim3(256), 0, stream>>>(
      input, memory, w_in, w_mem, scale, Qh, Kh, idot, mdot);
  tr_kernel<<<dim3(DDIM / 64, MDIM / 64, BDIM), dim3(256), 0, stream>>>(Kh, Vt);
  gemm1_kernel<<<dim3(BDIM * 8 * 8), dim3(512), 0, stream>>>(
      Qh, Kh, idot, mdot, mask, Sp);
  softmax_rows<<<dim3(BDIM * LDIM / 4), dim3(256), 0, stream>>>(Sp, rmax);
  w2a_kernel<<<dim3(BDIM), dim3(256), 0, stream>>>(rmax, w2);
  o2init_kernel<<<dim3(BDIM * DDIM / 256), dim3(256), 0, stream>>>(o2);
  o2_kernel<<<dim3(LDIM / 128, BDIM), dim3(256), 0, stream>>>(input, w2, o2);
  gemm2_kernel<<<dim3(BDIM * 8 * 4), dim3(512), 0, stream>>>(
      Sp, Vt, input, o2, out);
}

// Round 5
// 653.186 us; speedup vs baseline: 1.1551x; 1.1551x over previous
//
#include <hip/hip_runtime.h>
#include <hip/hip_bf16.h>

// BiAttention: B=16, L=M=2048, D=1024.
//  conv -> tr -> gemm1(S=QK^T+dots,mask) -> softmax_rows -> w2a -> o2 -> gemm2(fused epilogue)
// R5: GEMMs = m97 template exactly: 128x128 tile, 4 waves, BK=64, single-buffer
// 32KB LDS, plain __syncthreads 2-barrier K-loop (compiler waitcnts), GL16
// width-16, zero-conflict xor swizzle (verified R3), XCD swizzle,
// __launch_bounds__(256,3) => ~164 regs => 3 blocks/CU for cross-block overlap.

#define BDIM 16
#define LDIM 2048
#define MDIM 2048
#define DDIM 1024
#define NEGF (-60000.0f)

typedef float    f32x4v __attribute__((ext_vector_type(4)));
typedef _Float16 half8  __attribute__((ext_vector_type(8)));
typedef _Float16 half4  __attribute__((ext_vector_type(4)));

#define GL16(gp, lp)                                                        \
  __builtin_amdgcn_global_load_lds(                                         \
      (const __attribute__((address_space(1))) unsigned int*)(gp),          \
      (__attribute__((address_space(3))) unsigned int*)(lp), 16, 0, 0)

// ---------------- conversion + row dots ----------------
__global__ __launch_bounds__(256) void conv_kernel(
    const float* __restrict__ input, const float* __restrict__ memory,
    const float* __restrict__ w_in, const float* __restrict__ w_mem,
    const float* __restrict__ scale,
    _Float16* __restrict__ Qh, _Float16* __restrict__ Kh,
    float* __restrict__ idot, float* __restrict__ mdot) {
  const int t = threadIdx.x, lane = t & 63, wid = t >> 6;
  const size_t row = (size_t)blockIdx.x * 4 + wid;
  const float* ir  = input  + row * DDIM;
  const float* mrp = memory + row * DDIM;
  float di = 0.f, dm = 0.f;
#pragma unroll
  for (int c = 0; c < 4; ++c) {
    const int off = c * 256 + lane * 4;
    float4 sc4 = *(const float4*)&scale[off];
    float4 wi4 = *(const float4*)&w_in[off];
    float4 wm4 = *(const float4*)&w_mem[off];
    float4 v = *(const float4*)&ir[off];
    di += v.x * wi4.x + v.y * wi4.y + v.z * wi4.z + v.w * wi4.w;
    half4 q = { (_Float16)(v.x * sc4.x), (_Float16)(v.y * sc4.y),
                (_Float16)(v.z * sc4.z), (_Float16)(v.w * sc4.w) };
    *(half4*)&Qh[row * DDIM + off] = q;
    float4 u = *(const float4*)&mrp[off];
    dm += u.x * wm4.x + u.y * wm4.y + u.z * wm4.z + u.w * wm4.w;
    half4 k = { (_Float16)u.x, (_Float16)u.y, (_Float16)u.z, (_Float16)u.w };
    *(half4*)&Kh[row * DDIM + off] = k;
  }
#pragma unroll
  for (int o = 1; o < 64; o <<= 1) {
    di += __shfl_xor(di, o, 64);
    dm += __shfl_xor(dm, o, 64);
  }
  if (lane == 0) { idot[row] = di; mdot[row] = dm; }
}

// ---------------- transpose memory (f16) -> Vt[b][d][m] ----------------
__global__ __launch_bounds__(256) void tr_kernel(const _Float16* __restrict__ Kh,
                                                 _Float16* __restrict__ Vt) {
  const int b = blockIdx.z;
  const int d0 = blockIdx.x * 64, m0 = blockIdx.y * 64;
  __shared__ _Float16 sT[64][80];
  const int t = threadIdx.x;
  {
    const int mr = t >> 2, ch = (t & 3) * 16;
    const _Float16* src = Kh + ((size_t)b * MDIM + m0 + mr) * DDIM + d0 + ch;
    *(half8*)&sT[mr][ch]     = *(const half8*)&src[0];
    *(half8*)&sT[mr][ch + 8] = *(const half8*)&src[8];
  }
  __syncthreads();
  {
    const int dr = t >> 2, mc = (t & 3) * 16;
    union { _Float16 h[16]; half8 v[2]; } tmp;
#pragma unroll
    for (int j = 0; j < 16; ++j) tmp.h[j] = sT[mc + j][dr];
    _Float16* dst = Vt + ((size_t)b * DDIM + d0 + dr) * MDIM + m0 + mc;
    *(half8*)&dst[0] = tmp.v[0];
    *(half8*)&dst[8] = tmp.v[1];
  }
}

// ============ m97-style 128^2 GEMM core ============
// stage 128x64 K-tile of A and B; linear GL16 dest (lane*16B), source column
// chunk inverse-permuted so LDS slot q of row r holds source chunk q^(r&7).
__device__ __forceinline__ void stage128(const _Float16* __restrict__ Ab,
                                         const _Float16* __restrict__ Bb,
                                         _Float16* sAb, _Float16* sBb,
                                         int stride, int k0, int wid, int lane) {
  const int rsub = lane >> 3;                    // 0..7
  const int sc = ((lane & 7) ^ rsub) * 8;        // swizzled source col (halfs)
#pragma unroll
  for (int j = 0; j < 4; ++j) {
    const int r0 = wid * 32 + j * 8;
    const size_t go = (size_t)(r0 + rsub) * stride + k0 + sc;
    GL16(Ab + go, sAb + r0 * 64);
    GL16(Bb + go, sBb + r0 * 64);
  }
}

// one K=64 step: 16 ds_read_b128 (swizzled, conflict-free) + 32 MFMA
__device__ __forceinline__ void compute128(const _Float16* sAb, const _Float16* sBb,
                                           f32x4v acc[4][4], int wr, int wc,
                                           int lane) {
  const int l15 = lane & 15;
#pragma unroll
  for (int kk = 0; kk < 2; ++kk) {
    const int colh = ((kk * 4 + (lane >> 4)) ^ (lane & 7)) * 8;
    half8 aF[4], bF[4];
#pragma unroll
    for (int i = 0; i < 4; ++i) {
      aF[i] = *(const half8*)&sAb[(wr * 64 + i * 16 + l15) * 64 + colh];
      bF[i] = *(const half8*)&sBb[(wc * 64 + i * 16 + l15) * 64 + colh];
    }
#pragma unroll
    for (int mi = 0; mi < 4; ++mi)
#pragma unroll
      for (int ni = 0; ni < 4; ++ni)
        acc[mi][ni] = __builtin_amdgcn_mfma_f32_16x16x32_f16(aF[mi], bF[ni],
                                                             acc[mi][ni], 0, 0, 0);
  }
}

// ---------------- GEMM1: S = Q @ K^T + dots, masked ----------------
__global__ __launch_bounds__(256, 3) void gemm1_kernel(
    const _Float16* __restrict__ Qh, const _Float16* __restrict__ Kh,
    const float* __restrict__ idot, const float* __restrict__ mdot,
    const int* __restrict__ mask, _Float16* __restrict__ Sp) {
  const int id = blockIdx.x;                  // nwg = 4096
  const int wg = (id & 7) * 512 + (id >> 3);
  const int b = wg >> 8, rem = wg & 255, by = rem >> 4, bx = rem & 15;
  const int t = threadIdx.x, lane = t & 63, wid = t >> 6;
  const int wr = wid >> 1, wc = wid & 1;
  __shared__ _Float16 sA[128 * 64];
  __shared__ _Float16 sB[128 * 64];
  __shared__ float s_dl[128], s_dm[128];
  __shared__ int   s_ml[128], s_mm[128];
  if (t < 128) {
    s_dl[t] = idot[b * LDIM + by * 128 + t];
    s_ml[t] = mask[b * LDIM + by * 128 + t];
    s_dm[t] = mdot[b * MDIM + bx * 128 + t];
    s_mm[t] = mask[b * MDIM + bx * 128 + t];
  }
  const _Float16* Ab = Qh + ((size_t)b * LDIM + by * 128) * DDIM;
  const _Float16* Bb = Kh + ((size_t)b * MDIM + bx * 128) * DDIM;
  f32x4v acc[4][4];
#pragma unroll
  for (int i = 0; i < 4; ++i)
#pragma unroll
    for (int j = 0; j < 4; ++j) acc[i][j] = (f32x4v){0.f, 0.f, 0.f, 0.f};

  for (int ks = 0; ks < DDIM / 64; ++ks) {
    __syncthreads();
    stage128(Ab, Bb, sA, sB, DDIM, ks * 64, wid, lane);
    __syncthreads();
    compute128(sA, sB, acc, wr, wc, lane);
  }

  const int rb = wr * 64, cb = wc * 64;
#pragma unroll
  for (int mi = 0; mi < 4; ++mi)
#pragma unroll
    for (int ni = 0; ni < 4; ++ni)
#pragma unroll
      for (int r = 0; r < 4; ++r) {
        const int lrow = rb + mi * 16 + (lane >> 4) * 4 + r;
        const int lcol = cb + ni * 16 + (lane & 15);
        float s = acc[mi][ni][r] + s_dl[lrow] + s_dm[lcol];
        if ((s_ml[lrow] | s_mm[lcol]) != 0) s = NEGF;
        Sp[((size_t)b * LDIM + by * 128 + lrow) * MDIM + bx * 128 + lcol] = (_Float16)s;
      }
}

// ---------------- per-row softmax (in place) + rowmax ----------------
__global__ __launch_bounds__(256) void softmax_rows(_Float16* __restrict__ Sp,
                                                    float* __restrict__ rmax) {
  const int t = threadIdx.x, lane = t & 63, wid = t >> 6;
  const size_t row = (size_t)blockIdx.x * 4 + wid;
  _Float16* rp = Sp + row * (size_t)MDIM;
  float s[32];
#pragma unroll
  for (int c = 0; c < 4; ++c) {
    half8 v = *(const half8*)&rp[c * 512 + lane * 8];
#pragma unroll
    for (int j = 0; j < 8; ++j) s[c * 8 + j] = (float)v[j];
  }
  float m = -3.0e38f;
#pragma unroll
  for (int i = 0; i < 32; ++i) m = fmaxf(m, s[i]);
#pragma unroll
  for (int o = 1; o < 64; o <<= 1) m = fmaxf(m, __shfl_xor(m, o, 64));
  float sum = 0.f;
#pragma unroll
  for (int i = 0; i < 32; ++i) { s[i] = __expf(s[i] - m); sum += s[i]; }
#pragma unroll
  for (int o = 1; o < 64; o <<= 1) sum += __shfl_xor(sum, o, 64);
  const float inv = 1.f / sum;
#pragma unroll
  for (int c = 0; c < 4; ++c) {
    half8 v;
#pragma unroll
    for (int j = 0; j < 8; ++j) v[j] = (_Float16)(s[c * 8 + j] * inv);
    *(half8*)&rp[c * 512 + lane * 8] = v;
  }
  if (lane == 0) rmax[row] = m;
}

// ---------------- w2 = softmax_l(rowmax) per batch ----------------
__global__ __launch_bounds__(256) void w2a_kernel(const float* __restrict__ rmax,
                                                  float* __restrict__ w2) {
  const int b = blockIdx.x, t = threadIdx.x;
  __shared__ float red[256];
  const float* rm = rmax + (size_t)b * LDIM;
  float vals[8]; float lm = -3.0e38f;
#pragma unroll
  for (int j = 0; j < 8; ++j) { vals[j] = rm[t + j * 256]; lm = fmaxf(lm, vals[j]); }
  red[t] = lm; __syncthreads();
  for (int s = 128; s > 0; s >>= 1) {
    if (t < s) red[t] = fmaxf(red[t], red[t + s]);
    __syncthreads();
  }
  const float M = red[0]; __syncthreads();
  float ls = 0.f;
#pragma unroll
  for (int j = 0; j < 8; ++j) ls += __expf(vals[j] - M);
  red[t] = ls; __syncthreads();
  for (int s = 128; s > 0; s >>= 1) {
    if (t < s) red[t] += red[t + s];
    __syncthreads();
  }
  const float inv = 1.f / red[0];
#pragma unroll
  for (int j = 0; j < 8; ++j) w2[(size_t)b * LDIM + t + j * 256] = __expf(vals[j] - M) * inv;
}

// ---------------- o2 ----------------
__global__ void o2init_kernel(float* __restrict__ o2) {
  o2[blockIdx.x * 256 + threadIdx.x] = 0.f;
}

__global__ __launch_bounds__(256) void o2_kernel(const float* __restrict__ input,
                                                 const float* __restrict__ w2,
                                                 float* __restrict__ o2) {
  const int b = blockIdx.y, ch = blockIdx.x, t = threadIdx.x;
  __shared__ float sw[128];
  if (t < 128) sw[t] = w2[(size_t)b * LDIM + ch * 128 + t];
  __syncthreads();
  const float* ib = input + ((size_t)b * LDIM + ch * 128) * DDIM;
  float4 acc = {0.f, 0.f, 0.f, 0.f};
  for (int l = 0; l < 128; ++l) {
    const float w = sw[l];
    float4 v = *(const float4*)&ib[(size_t)l * DDIM + t * 4];
    acc.x += w * v.x; acc.y += w * v.y; acc.z += w * v.z; acc.w += w * v.w;
  }
  atomicAdd(&o2[b * DDIM + t * 4 + 0], acc.x);
  atomicAdd(&o2[b * DDIM + t * 4 + 1], acc.y);
  atomicAdd(&o2[b * DDIM + t * 4 + 2], acc.z);
  atomicAdd(&o2[b * DDIM + t * 4 + 3], acc.w);
}

// ---------------- GEMM2: o1 = P @ V, fused epilogue ----------------
__global__ __launch_bounds__(256, 3) void gemm2_kernel(
    const _Float16* __restrict__ Pm, const _Float16* __restrict__ Vt,
    const float* __restrict__ input, const float* __restrict__ o2,
    float* __restrict__ out) {
  const int id = blockIdx.x;                  // nwg = 2048
  const int wg = (id & 7) * 256 + (id >> 3);
  const int b = wg >> 7, rem = wg & 127, by = rem >> 3, bx = rem & 7;
  const int t = threadIdx.x, lane = t & 63, wid = t >> 6;
  const int wr = wid >> 1, wc = wid & 1;
  __shared__ _Float16 sA[128 * 64];
  __shared__ _Float16 sB[128 * 64];
  const _Float16* Ab = Pm + ((size_t)b * LDIM + by * 128) * MDIM;
  const _Float16* Bb = Vt + ((size_t)b * DDIM + bx * 128) * MDIM;
  f32x4v acc[4][4];
#pragma unroll
  for (int i = 0; i < 4; ++i)
#pragma unroll
    for (int j = 0; j < 4; ++j) acc[i][j] = (f32x4v){0.f, 0.f, 0.f, 0.f};

  for (int ks = 0; ks < MDIM / 64; ++ks) {
    __syncthreads();
    stage128(Ab, Bb, sA, sB, MDIM, ks * 64, wid, lane);
    __syncthreads();
    compute128(sA, sB, acc, wr, wc, lane);
  }

  const int rb = wr * 64, cb = wc * 64;
#pragma unroll
  for (int mi = 0; mi < 4; ++mi)
#pragma unroll
    for (int ni = 0; ni < 4; ++ni)
#pragma unroll
      for (int r = 0; r < 4; ++r) {
        const int lrow = rb + mi * 16 + (lane >> 4) * 4 + r;
        const int lcol = cb + ni * 16 + (lane & 15);
        const size_t l = (size_t)by * 128 + lrow;
        const int d = bx * 128 + lcol;
        const float o1 = acc[mi][ni][r];
        const float inp = input[((size_t)b * LDIM + l) * DDIM + d];
        const float o2v = o2[b * DDIM + d];
        const size_t ob = ((size_t)b * LDIM + l) * (4 * DDIM) + d;
        out[ob] = inp;
        out[ob + DDIM] = o1;
        out[ob + 2 * DDIM] = inp * o1;
        out[ob + 3 * DDIM] = o2v * o1;
      }
}

extern "C" void kernel_launch(void* const* d_in, const int* in_sizes, int n_in,
                              void* d_out, int out_size, void* d_ws, size_t ws_size,
                              hipStream_t stream) {
  (void)in_sizes; (void)n_in; (void)out_size; (void)ws_size;
  const float* input  = (const float*)d_in[0];
  const float* memory = (const float*)d_in[1];
  const int*   mask   = (const int*)d_in[2];
  const float* w_in   = (const float*)d_in[3];
  const float* w_mem  = (const float*)d_in[4];
  const float* scale  = (const float*)d_in[5];
  float* out = (float*)d_out;

  char* p = (char*)d_ws;
  _Float16* Qh = (_Float16*)p; p += (size_t)BDIM * LDIM * DDIM * 2;
  _Float16* Kh = (_Float16*)p; p += (size_t)BDIM * MDIM * DDIM * 2;
  _Float16* Vt = (_Float16*)p; p += (size_t)BDIM * DDIM * MDIM * 2;
  _Float16* Sp = (_Float16*)p; p += (size_t)BDIM * LDIM * MDIM * 2;
  float* idot = (float*)p; p += (size_t)BDIM * LDIM * 4;
  float* mdot = (float*)p; p += (size_t)BDIM * MDIM * 4;
  float* rmax = (float*)p; p += (size_t)BDIM * LDIM * 4;
  float* w2   = (float*)p; p += (size_t)BDIM * LDIM * 4;
  float* o2   = (float*)p; p += (size_t)BDIM * DDIM * 4;

  conv_kernel<<<dim3(BDIM * LDIM / 4), dim3(256), 0, stream>>>(
      input, memory, w_in, w_mem, scale, Qh, Kh, idot, mdot);
  tr_kernel<<<dim3(DDIM / 64, MDIM / 64, BDIM), dim3(256), 0, stream>>>(Kh, Vt);
  gemm1_kernel<<<dim3(BDIM * 16 * 16), dim3(256), 0, stream>>>(
      Qh, Kh, idot, mdot, mask, Sp);
  softmax_rows<<<dim3(BDIM * LDIM / 4), dim3(256), 0, stream>>>(Sp, rmax);
  w2a_kernel<<<dim3(BDIM), dim3(256), 0, stream>>>(rmax, w2);
  o2init_kernel<<<dim3(BDIM * DDIM / 256), dim3(256), 0, stream>>>(o2);
  o2_kernel<<<dim3(LDIM / 128, BDIM), dim3(256), 0, stream>>>(input, w2, o2);
  gemm2_kernel<<<dim3(BDIM * 16 * 8), dim3(256), 0, stream>>>(
      Sp, Vt, input, o2, out);
}

// Round 6
// 645.418 us; speedup vs baseline: 1.1690x; 1.0120x over previous
//
#include <hip/hip_runtime.h>
#include <hip/hip_bf16.h>

// BiAttention: B=16, L=M=2048, D=1024.
//  conv -> tr -> gemm1(S=QK^T+dots,mask) -> softmax_rows -> w2a(+o2 zero) -> o2 -> gemm2(fused epilogue)
// R6: gemm1 = faithful fine-phase counted-vmcnt pipeline (T3+T4+T5):
//   256^2 tile, BK=32, 8 waves, ring-3 LDS (96KB), stage t+2 during t
//   (slot == t-1's, WAR-safe), per-phase {ds;stage;bar;prio;16 MFMA;prio;bar},
//   boundary vmcnt(4) (counted, never 0 mid-loop). No sched_barrier (m141 trap).
// gemm2 = R5 m97 structure (proven) + nontemporal output stores.

#define BDIM 16
#define LDIM 2048
#define MDIM 2048
#define DDIM 1024
#define NEGF (-60000.0f)

typedef float    f32x4v __attribute__((ext_vector_type(4)));
typedef _Float16 half8  __attribute__((ext_vector_type(8)));
typedef _Float16 half4  __attribute__((ext_vector_type(4)));

#define GL16(gp, lp)                                                        \
  __builtin_amdgcn_global_load_lds(                                         \
      (const __attribute__((address_space(1))) unsigned int*)(gp),          \
      (__attribute__((address_space(3))) unsigned int*)(lp), 16, 0, 0)

// ---------------- conversion + row dots ----------------
__global__ __launch_bounds__(256) void conv_kernel(
    const float* __restrict__ input, const float* __restrict__ memory,
    const float* __restrict__ w_in, const float* __restrict__ w_mem,
    const float* __restrict__ scale,
    _Float16* __restrict__ Qh, _Float16* __restrict__ Kh,
    float* __restrict__ idot, float* __restrict__ mdot) {
  const int t = threadIdx.x, lane = t & 63, wid = t >> 6;
  const size_t row = (size_t)blockIdx.x * 4 + wid;
  const float* ir  = input  + row * DDIM;
  const float* mrp = memory + row * DDIM;
  float di = 0.f, dm = 0.f;
#pragma unroll
  for (int c = 0; c < 4; ++c) {
    const int off = c * 256 + lane * 4;
    float4 sc4 = *(const float4*)&scale[off];
    float4 wi4 = *(const float4*)&w_in[off];
    float4 wm4 = *(const float4*)&w_mem[off];
    float4 v = *(const float4*)&ir[off];
    di += v.x * wi4.x + v.y * wi4.y + v.z * wi4.z + v.w * wi4.w;
    half4 q = { (_Float16)(v.x * sc4.x), (_Float16)(v.y * sc4.y),
                (_Float16)(v.z * sc4.z), (_Float16)(v.w * sc4.w) };
    *(half4*)&Qh[row * DDIM + off] = q;
    float4 u = *(const float4*)&mrp[off];
    dm += u.x * wm4.x + u.y * wm4.y + u.z * wm4.z + u.w * wm4.w;
    half4 k = { (_Float16)u.x, (_Float16)u.y, (_Float16)u.z, (_Float16)u.w };
    *(half4*)&Kh[row * DDIM + off] = k;
  }
#pragma unroll
  for (int o = 1; o < 64; o <<= 1) {
    di += __shfl_xor(di, o, 64);
    dm += __shfl_xor(dm, o, 64);
  }
  if (lane == 0) { idot[row] = di; mdot[row] = dm; }
}

// ---------------- transpose memory (f16) -> Vt[b][d][m] ----------------
__global__ __launch_bounds__(256) void tr_kernel(const _Float16* __restrict__ Kh,
                                                 _Float16* __restrict__ Vt) {
  const int b = blockIdx.z;
  const int d0 = blockIdx.x * 64, m0 = blockIdx.y * 64;
  __shared__ _Float16 sT[64][80];
  const int t = threadIdx.x;
  {
    const int mr = t >> 2, ch = (t & 3) * 16;
    const _Float16* src = Kh + ((size_t)b * MDIM + m0 + mr) * DDIM + d0 + ch;
    *(half8*)&sT[mr][ch]     = *(const half8*)&src[0];
    *(half8*)&sT[mr][ch + 8] = *(const half8*)&src[8];
  }
  __syncthreads();
  {
    const int dr = t >> 2, mc = (t & 3) * 16;
    union { _Float16 h[16]; half8 v[2]; } tmp;
#pragma unroll
    for (int j = 0; j < 16; ++j) tmp.h[j] = sT[mc + j][dr];
    _Float16* dst = Vt + ((size_t)b * DDIM + d0 + dr) * MDIM + m0 + mc;
    *(half8*)&dst[0] = tmp.v[0];
    *(half8*)&dst[8] = tmp.v[1];
  }
}

// ============ gemm1: fine-phase 256x256xBK32 pipeline ============
// stage one 256x32 tile of one matrix (2 GL16/thread). LDS chunk p = lane&3 at
// row r holds source chunk p ^ ((r>>1)&3)  => ds_read is exact 2-way (free).
__device__ __forceinline__ void stage256x32(const _Float16* __restrict__ src,
                                            _Float16* dst, int stride, int k0,
                                            int wid, int lane) {
#pragma unroll
  for (int c = 0; c < 2; ++c) {
    const int r = c * 128 + wid * 16 + (lane >> 2);
    const int q = (lane & 3) ^ ((r >> 1) & 3);
    GL16(src + (size_t)r * stride + k0 + q * 8, dst + (c * 128 + wid * 16) * 32);
  }
}

__device__ __forceinline__ half8 ldsfrag(const _Float16* s, int r, int kq) {
  return *(const half8*)&s[r * 32 + ((kq ^ ((r >> 1) & 3)) << 3)];
}

__global__ __launch_bounds__(512, 2) void gemm1_kernel(
    const _Float16* __restrict__ Qh, const _Float16* __restrict__ Kh,
    const float* __restrict__ idot, const float* __restrict__ mdot,
    const int* __restrict__ mask, _Float16* __restrict__ Sp) {
  const int id = blockIdx.x;                 // nwg = 1024
  const int wg = (id & 7) * 128 + (id >> 3);
  const int b = wg >> 6, rem = wg & 63, by = rem >> 3, bx = rem & 7;
  const int t = threadIdx.x, lane = t & 63, wid = t >> 6;
  const int wrow = wid >> 2, wcol = wid & 3;
  __shared__ _Float16 sA[3][256 * 32];
  __shared__ _Float16 sB[3][256 * 32];
  __shared__ float s_dl[256], s_dm[256];
  __shared__ int   s_ml[256], s_mm[256];
  if (t < 256) {
    s_dl[t] = idot[b * LDIM + by * 256 + t];
    s_ml[t] = mask[b * LDIM + by * 256 + t];
    s_dm[t] = mdot[b * MDIM + bx * 256 + t];
    s_mm[t] = mask[b * MDIM + bx * 256 + t];
  }
  const _Float16* Ab = Qh + ((size_t)b * LDIM + by * 256) * DDIM;
  const _Float16* Bb = Kh + ((size_t)b * MDIM + bx * 256) * DDIM;
  constexpr int NT = DDIM / 32;              // 32 K-tiles
  f32x4v acc[8][4];
#pragma unroll
  for (int i = 0; i < 8; ++i)
#pragma unroll
    for (int j = 0; j < 4; ++j) acc[i][j] = (f32x4v){0.f, 0.f, 0.f, 0.f};

  // prologue: stage tiles 0,1 (8 loads/thread); wait tile 0 (counted)
  stage256x32(Ab, sA[0], DDIM, 0, wid, lane);
  stage256x32(Bb, sB[0], DDIM, 0, wid, lane);
  stage256x32(Ab, sA[1], DDIM, 32, wid, lane);
  stage256x32(Bb, sB[1], DDIM, 32, wid, lane);
  asm volatile("s_waitcnt vmcnt(4)" ::: "memory");
  __builtin_amdgcn_s_barrier();

  const int kq = lane >> 4, l15 = lane & 15;
  int sl = 0;
  for (int tt = 0; tt < NT; ++tt) {
    const _Float16* cA = sA[sl];
    const _Float16* cB = sB[sl];
    const int sn = (sl + 2 >= 3) ? sl - 1 : sl + 2;   // slot of tile tt+2
    // ---- phase 0: ds 8, stage A(t+2), 16 MFMA (mi 0..3) ----
    half8 aF[4], bF[4];
#pragma unroll
    for (int mi = 0; mi < 4; ++mi) aF[mi] = ldsfrag(cA, wrow * 128 + mi * 16 + l15, kq);
#pragma unroll
    for (int ni = 0; ni < 4; ++ni) bF[ni] = ldsfrag(cB, wcol * 64 + ni * 16 + l15, kq);
    if (tt + 2 < NT) stage256x32(Ab, sA[sn], DDIM, (tt + 2) * 32, wid, lane);
    __builtin_amdgcn_s_barrier();
    __builtin_amdgcn_s_setprio(1);
#pragma unroll
    for (int mi = 0; mi < 4; ++mi)
#pragma unroll
      for (int ni = 0; ni < 4; ++ni)
        acc[mi][ni] = __builtin_amdgcn_mfma_f32_16x16x32_f16(aF[mi], bF[ni], acc[mi][ni], 0, 0, 0);
    __builtin_amdgcn_s_setprio(0);
    __builtin_amdgcn_s_barrier();
    // ---- phase 1: ds 4, stage B(t+2), 16 MFMA (mi 4..7) ----
    half8 aG[4];
#pragma unroll
    for (int mi = 0; mi < 4; ++mi) aG[mi] = ldsfrag(cA, wrow * 128 + (mi + 4) * 16 + l15, kq);
    if (tt + 2 < NT) stage256x32(Bb, sB[sn], DDIM, (tt + 2) * 32, wid, lane);
    __builtin_amdgcn_s_barrier();
    __builtin_amdgcn_s_setprio(1);
#pragma unroll
    for (int mi = 0; mi < 4; ++mi)
#pragma unroll
      for (int ni = 0; ni < 4; ++ni)
        acc[mi + 4][ni] = __builtin_amdgcn_mfma_f32_16x16x32_f16(aG[mi], bF[ni], acc[mi + 4][ni], 0, 0, 0);
    __builtin_amdgcn_s_setprio(0);
    // boundary: tile tt+1 must be resident (counted wait, never 0 mid-loop)
    if (tt < NT - 2)       asm volatile("s_waitcnt vmcnt(4)" ::: "memory");
    else if (tt == NT - 2) asm volatile("s_waitcnt vmcnt(0)" ::: "memory");
    __builtin_amdgcn_s_barrier();
    sl = (sl + 1 == 3) ? 0 : sl + 1;
  }

  const int rb = wrow * 128, cb = wcol * 64;
#pragma unroll
  for (int mi = 0; mi < 8; ++mi)
#pragma unroll
    for (int ni = 0; ni < 4; ++ni)
#pragma unroll
      for (int r = 0; r < 4; ++r) {
        const int lrow = rb + mi * 16 + (lane >> 4) * 4 + r;
        const int lcol = cb + ni * 16 + (lane & 15);
        float s = acc[mi][ni][r] + s_dl[lrow] + s_dm[lcol];
        if ((s_ml[lrow] | s_mm[lcol]) != 0) s = NEGF;
        Sp[((size_t)b * LDIM + by * 256 + lrow) * MDIM + bx * 256 + lcol] = (_Float16)s;
      }
}

// ---------------- per-row softmax (in place) + rowmax ----------------
__global__ __launch_bounds__(256) void softmax_rows(_Float16* __restrict__ Sp,
                                                    float* __restrict__ rmax) {
  const int t = threadIdx.x, lane = t & 63, wid = t >> 6;
  const size_t row = (size_t)blockIdx.x * 4 + wid;
  _Float16* rp = Sp + row * (size_t)MDIM;
  float s[32];
#pragma unroll
  for (int c = 0; c < 4; ++c) {
    half8 v = *(const half8*)&rp[c * 512 + lane * 8];
#pragma unroll
    for (int j = 0; j < 8; ++j) s[c * 8 + j] = (float)v[j];
  }
  float m = -3.0e38f;
#pragma unroll
  for (int i = 0; i < 32; ++i) m = fmaxf(m, s[i]);
#pragma unroll
  for (int o = 1; o < 64; o <<= 1) m = fmaxf(m, __shfl_xor(m, o, 64));
  float sum = 0.f;
#pragma unroll
  for (int i = 0; i < 32; ++i) { s[i] = __expf(s[i] - m); sum += s[i]; }
#pragma unroll
  for (int o = 1; o < 64; o <<= 1) sum += __shfl_xor(sum, o, 64);
  const float inv = 1.f / sum;
#pragma unroll
  for (int c = 0; c < 4; ++c) {
    half8 v;
#pragma unroll
    for (int j = 0; j < 8; ++j) v[j] = (_Float16)(s[c * 8 + j] * inv);
    *(half8*)&rp[c * 512 + lane * 8] = v;
  }
  if (lane == 0) rmax[row] = m;
}

// ---------------- w2 = softmax_l(rowmax) per batch (+ zero o2) ----------------
__global__ __launch_bounds__(256) void w2a_kernel(const float* __restrict__ rmax,
                                                  float* __restrict__ w2,
                                                  float* __restrict__ o2) {
  const int b = blockIdx.x, t = threadIdx.x;
  ((float4*)(o2 + (size_t)b * DDIM))[t] = (float4){0.f, 0.f, 0.f, 0.f};
  __shared__ float red[256];
  const float* rm = rmax + (size_t)b * LDIM;
  float vals[8]; float lm = -3.0e38f;
#pragma unroll
  for (int j = 0; j < 8; ++j) { vals[j] = rm[t + j * 256]; lm = fmaxf(lm, vals[j]); }
  red[t] = lm; __syncthreads();
  for (int s = 128; s > 0; s >>= 1) {
    if (t < s) red[t] = fmaxf(red[t], red[t + s]);
    __syncthreads();
  }
  const float M = red[0]; __syncthreads();
  float ls = 0.f;
#pragma unroll
  for (int j = 0; j < 8; ++j) ls += __expf(vals[j] - M);
  red[t] = ls; __syncthreads();
  for (int s = 128; s > 0; s >>= 1) {
    if (t < s) red[t] += red[t + s];
    __syncthreads();
  }
  const float inv = 1.f / red[0];
#pragma unroll
  for (int j = 0; j < 8; ++j) w2[(size_t)b * LDIM + t + j * 256] = __expf(vals[j] - M) * inv;
}

// ---------------- o2 ----------------
__global__ __launch_bounds__(256) void o2_kernel(const float* __restrict__ input,
                                                 const float* __restrict__ w2,
                                                 float* __restrict__ o2) {
  const int b = blockIdx.y, ch = blockIdx.x, t = threadIdx.x;
  __shared__ float sw[128];
  if (t < 128) sw[t] = w2[(size_t)b * LDIM + ch * 128 + t];
  __syncthreads();
  const float* ib = input + ((size_t)b * LDIM + ch * 128) * DDIM;
  float4 acc = {0.f, 0.f, 0.f, 0.f};
  for (int l = 0; l < 128; ++l) {
    const float w = sw[l];
    float4 v = *(const float4*)&ib[(size_t)l * DDIM + t * 4];
    acc.x += w * v.x; acc.y += w * v.y; acc.z += w * v.z; acc.w += w * v.w;
  }
  atomicAdd(&o2[b * DDIM + t * 4 + 0], acc.x);
  atomicAdd(&o2[b * DDIM + t * 4 + 1], acc.y);
  atomicAdd(&o2[b * DDIM + t * 4 + 2], acc.z);
  atomicAdd(&o2[b * DDIM + t * 4 + 3], acc.w);
}

// ============ gemm2: m97-style 128^2 (R5, proven) + nt stores ============
__device__ __forceinline__ void stage128(const _Float16* __restrict__ Ab,
                                         const _Float16* __restrict__ Bb,
                                         _Float16* sAb, _Float16* sBb,
                                         int stride, int k0, int wid, int lane) {
  const int rsub = lane >> 3;
  const int sc = ((lane & 7) ^ rsub) * 8;
#pragma unroll
  for (int j = 0; j < 4; ++j) {
    const int r0 = wid * 32 + j * 8;
    const size_t go = (size_t)(r0 + rsub) * stride + k0 + sc;
    GL16(Ab + go, sAb + r0 * 64);
    GL16(Bb + go, sBb + r0 * 64);
  }
}

__device__ __forceinline__ void compute128(const _Float16* sAb, const _Float16* sBb,
                                           f32x4v acc[4][4], int wr, int wc,
                                           int lane) {
  const int l15 = lane & 15;
#pragma unroll
  for (int kk = 0; kk < 2; ++kk) {
    const int colh = ((kk * 4 + (lane >> 4)) ^ (lane & 7)) * 8;
    half8 aF[4], bF[4];
#pragma unroll
    for (int i = 0; i < 4; ++i) {
      aF[i] = *(const half8*)&sAb[(wr * 64 + i * 16 + l15) * 64 + colh];
      bF[i] = *(const half8*)&sBb[(wc * 64 + i * 16 + l15) * 64 + colh];
    }
#pragma unroll
    for (int mi = 0; mi < 4; ++mi)
#pragma unroll
      for (int ni = 0; ni < 4; ++ni)
        acc[mi][ni] = __builtin_amdgcn_mfma_f32_16x16x32_f16(aF[mi], bF[ni],
                                                             acc[mi][ni], 0, 0, 0);
  }
}

__global__ __launch_bounds__(256, 3) void gemm2_kernel(
    const _Float16* __restrict__ Pm, const _Float16* __restrict__ Vt,
    const float* __restrict__ input, const float* __restrict__ o2,
    float* __restrict__ out) {
  const int id = blockIdx.x;                  // nwg = 2048
  const int wg = (id & 7) * 256 + (id >> 3);
  const int b = wg >> 7, rem = wg & 127, by = rem >> 3, bx = rem & 7;
  const int t = threadIdx.x, lane = t & 63, wid = t >> 6;
  const int wr = wid >> 1, wc = wid & 1;
  __shared__ _Float16 sA[128 * 64];
  __shared__ _Float16 sB[128 * 64];
  const _Float16* Ab = Pm + ((size_t)b * LDIM + by * 128) * MDIM;
  const _Float16* Bb = Vt + ((size_t)b * DDIM + bx * 128) * MDIM;
  f32x4v acc[4][4];
#pragma unroll
  for (int i = 0; i < 4; ++i)
#pragma unroll
    for (int j = 0; j < 4; ++j) acc[i][j] = (f32x4v){0.f, 0.f, 0.f, 0.f};

  for (int ks = 0; ks < MDIM / 64; ++ks) {
    __syncthreads();
    stage128(Ab, Bb, sA, sB, MDIM, ks * 64, wid, lane);
    __syncthreads();
    compute128(sA, sB, acc, wr, wc, lane);
  }

  const int rb = wr * 64, cb = wc * 64;
#pragma unroll
  for (int mi = 0; mi < 4; ++mi)
#pragma unroll
    for (int ni = 0; ni < 4; ++ni)
#pragma unroll
      for (int r = 0; r < 4; ++r) {
        const int lrow = rb + mi * 16 + (lane >> 4) * 4 + r;
        const int lcol = cb + ni * 16 + (lane & 15);
        const size_t l = (size_t)by * 128 + lrow;
        const int d = bx * 128 + lcol;
        const float o1 = acc[mi][ni][r];
        const float inp = input[((size_t)b * LDIM + l) * DDIM + d];
        const float o2v = o2[b * DDIM + d];
        const size_t ob = ((size_t)b * LDIM + l) * (4 * DDIM) + d;
        __builtin_nontemporal_store(inp, &out[ob]);
        __builtin_nontemporal_store(o1, &out[ob + DDIM]);
        __builtin_nontemporal_store(inp * o1, &out[ob + 2 * DDIM]);
        __builtin_nontemporal_store(o2v * o1, &out[ob + 3 * DDIM]);
      }
}

extern "C" void kernel_launch(void* const* d_in, const int* in_sizes, int n_in,
                              void* d_out, int out_size, void* d_ws, size_t ws_size,
                              hipStream_t stream) {
  (void)in_sizes; (void)n_in; (void)out_size; (void)ws_size;
  const float* input  = (const float*)d_in[0];
  const float* memory = (const float*)d_in[1];
  const int*   mask   = (const int*)d_in[2];
  const float* w_in   = (const float*)d_in[3];
  const float* w_mem  = (const float*)d_in[4];
  const float* scale  = (const float*)d_in[5];
  float* out = (float*)d_out;

  char* p = (char*)d_ws;
  _Float16* Qh = (_Float16*)p; p += (size_t)BDIM * LDIM * DDIM * 2;
  _Float16* Kh = (_Float16*)p; p += (size_t)BDIM * MDIM * DDIM * 2;
  _Float16* Vt = (_Float16*)p; p += (size_t)BDIM * DDIM * MDIM * 2;
  _Float16* Sp = (_Float16*)p; p += (size_t)BDIM * LDIM * MDIM * 2;
  float* idot = (float*)p; p += (size_t)BDIM * LDIM * 4;
  float* mdot = (float*)p; p += (size_t)BDIM * MDIM * 4;
  float* rmax = (float*)p; p += (size_t)BDIM * LDIM * 4;
  float* w2   = (float*)p; p += (size_t)BDIM * LDIM * 4;
  float* o2   = (float*)p; p += (size_t)BDIM * DDIM * 4;

  conv_kernel<<<dim3(BDIM * LDIM / 4), dim3(256), 0, stream>>>(
      input, memory, w_in, w_mem, scale, Qh, Kh, idot, mdot);
  tr_kernel<<<dim3(DDIM / 64, MDIM / 64, BDIM), dim3(256), 0, stream>>>(Kh, Vt);
  gemm1_kernel<<<dim3(BDIM * 8 * 8), dim3(512), 0, stream>>>(
      Qh, Kh, idot, mdot, mask, Sp);
  softmax_rows<<<dim3(BDIM * LDIM / 4), dim3(256), 0, stream>>>(Sp, rmax);
  w2a_kernel<<<dim3(BDIM), dim3(256), 0, stream>>>(rmax, w2, o2);
  o2_kernel<<<dim3(LDIM / 128, BDIM), dim3(256), 0, stream>>>(input, w2, o2);
  gemm2_kernel<<<dim3(BDIM * 16 * 8), dim3(256), 0, stream>>>(
      Sp, Vt, input, o2, out);
}

// Round 8
// 551.443 us; speedup vs baseline: 1.3682x; 1.1704x over previous
//
#include <hip/hip_runtime.h>
#include <hip/hip_bf16.h>

// BiAttention: B=16, L=M=2048, D=1024.
//  conv -> tr -> gemm1(S=QK^T+dots,mask) -> softmax_rows -> w2a(+o2 zero) -> o2 -> gemm2(fused epilogue)
// R8 (= R7 + compile fix): both GEMMs = m97 128^2 2-barrier structure with:
//  - __launch_bounds__(256,4): 64 VGPR + 64 AGPR = 128 regs -> 4 blocks/CU.
//  - LDS-staged vectorized epilogues: gemm1 writes S as half8 rows; gemm2
//    stages 16x128 f32 panels and writes float4-wide nontemporal stores
//    (via clang ext_vector type; HIP float4* is rejected by the builtin).

#define BDIM 16
#define LDIM 2048
#define MDIM 2048
#define DDIM 1024
#define NEGF (-60000.0f)

typedef float    f32x4v __attribute__((ext_vector_type(4)));
typedef _Float16 half8  __attribute__((ext_vector_type(8)));
typedef _Float16 half4  __attribute__((ext_vector_type(4)));

#define GL16(gp, lp)                                                        \
  __builtin_amdgcn_global_load_lds(                                         \
      (const __attribute__((address_space(1))) unsigned int*)(gp),          \
      (__attribute__((address_space(3))) unsigned int*)(lp), 16, 0, 0)

__device__ __forceinline__ float4 m4(const float4 a, const float4 b) {
  return (float4){a.x * b.x, a.y * b.y, a.z * b.z, a.w * b.w};
}
__device__ __forceinline__ void nts4(const float4 v, float* p) {
  f32x4v w = {v.x, v.y, v.z, v.w};
  __builtin_nontemporal_store(w, (f32x4v*)p);
}

// ---------------- conversion + row dots ----------------
__global__ __launch_bounds__(256) void conv_kernel(
    const float* __restrict__ input, const float* __restrict__ memory,
    const float* __restrict__ w_in, const float* __restrict__ w_mem,
    const float* __restrict__ scale,
    _Float16* __restrict__ Qh, _Float16* __restrict__ Kh,
    float* __restrict__ idot, float* __restrict__ mdot) {
  const int t = threadIdx.x, lane = t & 63, wid = t >> 6;
  const size_t row = (size_t)blockIdx.x * 4 + wid;
  const float* ir  = input  + row * DDIM;
  const float* mrp = memory + row * DDIM;
  float di = 0.f, dm = 0.f;
#pragma unroll
  for (int c = 0; c < 4; ++c) {
    const int off = c * 256 + lane * 4;
    float4 sc4 = *(const float4*)&scale[off];
    float4 wi4 = *(const float4*)&w_in[off];
    float4 wm4 = *(const float4*)&w_mem[off];
    float4 v = *(const float4*)&ir[off];
    di += v.x * wi4.x + v.y * wi4.y + v.z * wi4.z + v.w * wi4.w;
    half4 q = { (_Float16)(v.x * sc4.x), (_Float16)(v.y * sc4.y),
                (_Float16)(v.z * sc4.z), (_Float16)(v.w * sc4.w) };
    *(half4*)&Qh[row * DDIM + off] = q;
    float4 u = *(const float4*)&mrp[off];
    dm += u.x * wm4.x + u.y * wm4.y + u.z * wm4.z + u.w * wm4.w;
    half4 k = { (_Float16)u.x, (_Float16)u.y, (_Float16)u.z, (_Float16)u.w };
    *(half4*)&Kh[row * DDIM + off] = k;
  }
#pragma unroll
  for (int o = 1; o < 64; o <<= 1) {
    di += __shfl_xor(di, o, 64);
    dm += __shfl_xor(dm, o, 64);
  }
  if (lane == 0) { idot[row] = di; mdot[row] = dm; }
}

// ---------------- transpose memory (f16) -> Vt[b][d][m] ----------------
__global__ __launch_bounds__(256) void tr_kernel(const _Float16* __restrict__ Kh,
                                                 _Float16* __restrict__ Vt) {
  const int b = blockIdx.z;
  const int d0 = blockIdx.x * 64, m0 = blockIdx.y * 64;
  __shared__ _Float16 sT[64][80];
  const int t = threadIdx.x;
  {
    const int mr = t >> 2, ch = (t & 3) * 16;
    const _Float16* src = Kh + ((size_t)b * MDIM + m0 + mr) * DDIM + d0 + ch;
    *(half8*)&sT[mr][ch]     = *(const half8*)&src[0];
    *(half8*)&sT[mr][ch + 8] = *(const half8*)&src[8];
  }
  __syncthreads();
  {
    const int dr = t >> 2, mc = (t & 3) * 16;
    union { _Float16 h[16]; half8 v[2]; } tmp;
#pragma unroll
    for (int j = 0; j < 16; ++j) tmp.h[j] = sT[mc + j][dr];
    _Float16* dst = Vt + ((size_t)b * DDIM + d0 + dr) * MDIM + m0 + mc;
    *(half8*)&dst[0] = tmp.v[0];
    *(half8*)&dst[8] = tmp.v[1];
  }
}

// ============ m97-style 128^2 GEMM core (R5, proven) ============
__device__ __forceinline__ void stage128(const _Float16* __restrict__ Ab,
                                         const _Float16* __restrict__ Bb,
                                         _Float16* sAb, _Float16* sBb,
                                         int stride, int k0, int wid, int lane) {
  const int rsub = lane >> 3;
  const int sc = ((lane & 7) ^ rsub) * 8;
#pragma unroll
  for (int j = 0; j < 4; ++j) {
    const int r0 = wid * 32 + j * 8;
    const size_t go = (size_t)(r0 + rsub) * stride + k0 + sc;
    GL16(Ab + go, sAb + r0 * 64);
    GL16(Bb + go, sBb + r0 * 64);
  }
}

__device__ __forceinline__ void compute128(const _Float16* sAb, const _Float16* sBb,
                                           f32x4v acc[4][4], int wr, int wc,
                                           int lane) {
  const int l15 = lane & 15;
#pragma unroll
  for (int kk = 0; kk < 2; ++kk) {
    const int colh = ((kk * 4 + (lane >> 4)) ^ (lane & 7)) * 8;
    half8 aF[4], bF[4];
#pragma unroll
    for (int i = 0; i < 4; ++i) {
      aF[i] = *(const half8*)&sAb[(wr * 64 + i * 16 + l15) * 64 + colh];
      bF[i] = *(const half8*)&sBb[(wc * 64 + i * 16 + l15) * 64 + colh];
    }
#pragma unroll
    for (int mi = 0; mi < 4; ++mi)
#pragma unroll
      for (int ni = 0; ni < 4; ++ni)
        acc[mi][ni] = __builtin_amdgcn_mfma_f32_16x16x32_f16(aF[mi], bF[ni],
                                                             acc[mi][ni], 0, 0, 0);
  }
}

// ---------------- GEMM1: S = Q @ K^T + dots, masked ----------------
__global__ __launch_bounds__(256, 4) void gemm1_kernel(
    const _Float16* __restrict__ Qh, const _Float16* __restrict__ Kh,
    const float* __restrict__ idot, const float* __restrict__ mdot,
    const int* __restrict__ mask, _Float16* __restrict__ Sp) {
  const int id = blockIdx.x;                  // nwg = 4096
  const int wg = (id & 7) * 512 + (id >> 3);
  const int b = wg >> 8, rem = wg & 255, by = rem >> 4, bx = rem & 15;
  const int t = threadIdx.x, lane = t & 63, wid = t >> 6;
  const int wr = wid >> 1, wc = wid & 1;
  __shared__ union SM1 {
    struct { _Float16 a[128 * 64]; _Float16 b[128 * 64]; } ab;
    _Float16 s[128 * 140];                     // padded S-tile stage
  } sm;
  __shared__ float s_dl[128], s_dm[128];
  __shared__ int   s_ml[128], s_mm[128];
  if (t < 128) {
    s_dl[t] = idot[b * LDIM + by * 128 + t];
    s_ml[t] = mask[b * LDIM + by * 128 + t];
    s_dm[t] = mdot[b * MDIM + bx * 128 + t];
    s_mm[t] = mask[b * MDIM + bx * 128 + t];
  }
  const _Float16* Ab = Qh + ((size_t)b * LDIM + by * 128) * DDIM;
  const _Float16* Bb = Kh + ((size_t)b * MDIM + bx * 128) * DDIM;
  f32x4v acc[4][4];
#pragma unroll
  for (int i = 0; i < 4; ++i)
#pragma unroll
    for (int j = 0; j < 4; ++j) acc[i][j] = (f32x4v){0.f, 0.f, 0.f, 0.f};

  for (int ks = 0; ks < DDIM / 64; ++ks) {
    __syncthreads();
    stage128(Ab, Bb, sm.ab.a, sm.ab.b, DDIM, ks * 64, wid, lane);
    __syncthreads();
    compute128(sm.ab.a, sm.ab.b, acc, wr, wc, lane);
  }

  // epilogue: stage f16 S-tile in LDS, then half8 row writes
  __syncthreads();
  const int rb = wr * 64, cb = wc * 64;
#pragma unroll
  for (int mi = 0; mi < 4; ++mi)
#pragma unroll
    for (int ni = 0; ni < 4; ++ni)
#pragma unroll
      for (int r = 0; r < 4; ++r) {
        const int lrow = rb + mi * 16 + (lane >> 4) * 4 + r;
        const int lcol = cb + ni * 16 + (lane & 15);
        float s = acc[mi][ni][r] + s_dl[lrow] + s_dm[lcol];
        if ((s_ml[lrow] | s_mm[lcol]) != 0) s = NEGF;
        sm.s[lrow * 140 + lcol] = (_Float16)s;
      }
  __syncthreads();
  const int r16 = t >> 4, c8 = (t & 15) * 8;
#pragma unroll
  for (int rd = 0; rd < 8; ++rd) {
    const int lrow = rd * 16 + r16;
    half8 v = *(const half8*)&sm.s[lrow * 140 + c8];
    *(half8*)&Sp[((size_t)b * LDIM + by * 128 + lrow) * MDIM + bx * 128 + c8] = v;
  }
}

// ---------------- per-row softmax (in place) + rowmax ----------------
__global__ __launch_bounds__(256) void softmax_rows(_Float16* __restrict__ Sp,
                                                    float* __restrict__ rmax) {
  const int t = threadIdx.x, lane = t & 63, wid = t >> 6;
  const size_t row = (size_t)blockIdx.x * 4 + wid;
  _Float16* rp = Sp + row * (size_t)MDIM;
  float s[32];
#pragma unroll
  for (int c = 0; c < 4; ++c) {
    half8 v = *(const half8*)&rp[c * 512 + lane * 8];
#pragma unroll
    for (int j = 0; j < 8; ++j) s[c * 8 + j] = (float)v[j];
  }
  float m = -3.0e38f;
#pragma unroll
  for (int i = 0; i < 32; ++i) m = fmaxf(m, s[i]);
#pragma unroll
  for (int o = 1; o < 64; o <<= 1) m = fmaxf(m, __shfl_xor(m, o, 64));
  float sum = 0.f;
#pragma unroll
  for (int i = 0; i < 32; ++i) { s[i] = __expf(s[i] - m); sum += s[i]; }
#pragma unroll
  for (int o = 1; o < 64; o <<= 1) sum += __shfl_xor(sum, o, 64);
  const float inv = 1.f / sum;
#pragma unroll
  for (int c = 0; c < 4; ++c) {
    half8 v;
#pragma unroll
    for (int j = 0; j < 8; ++j) v[j] = (_Float16)(s[c * 8 + j] * inv);
    *(half8*)&rp[c * 512 + lane * 8] = v;
  }
  if (lane == 0) rmax[row] = m;
}

// ---------------- w2 = softmax_l(rowmax) per batch (+ zero o2) ----------------
__global__ __launch_bounds__(256) void w2a_kernel(const float* __restrict__ rmax,
                                                  float* __restrict__ w2,
                                                  float* __restrict__ o2) {
  const int b = blockIdx.x, t = threadIdx.x;
  ((float4*)(o2 + (size_t)b * DDIM))[t] = (float4){0.f, 0.f, 0.f, 0.f};
  __shared__ float red[256];
  const float* rm = rmax + (size_t)b * LDIM;
  float vals[8]; float lm = -3.0e38f;
#pragma unroll
  for (int j = 0; j < 8; ++j) { vals[j] = rm[t + j * 256]; lm = fmaxf(lm, vals[j]); }
  red[t] = lm; __syncthreads();
  for (int s = 128; s > 0; s >>= 1) {
    if (t < s) red[t] = fmaxf(red[t], red[t + s]);
    __syncthreads();
  }
  const float M = red[0]; __syncthreads();
  float ls = 0.f;
#pragma unroll
  for (int j = 0; j < 8; ++j) ls += __expf(vals[j] - M);
  red[t] = ls; __syncthreads();
  for (int s = 128; s > 0; s >>= 1) {
    if (t < s) red[t] += red[t + s];
    __syncthreads();
  }
  const float inv = 1.f / red[0];
#pragma unroll
  for (int j = 0; j < 8; ++j) w2[(size_t)b * LDIM + t + j * 256] = __expf(vals[j] - M) * inv;
}

// ---------------- o2 ----------------
__global__ __launch_bounds__(256) void o2_kernel(const float* __restrict__ input,
                                                 const float* __restrict__ w2,
                                                 float* __restrict__ o2) {
  const int b = blockIdx.y, ch = blockIdx.x, t = threadIdx.x;
  __shared__ float sw[128];
  if (t < 128) sw[t] = w2[(size_t)b * LDIM + ch * 128 + t];
  __syncthreads();
  const float* ib = input + ((size_t)b * LDIM + ch * 128) * DDIM;
  float4 acc = {0.f, 0.f, 0.f, 0.f};
  for (int l = 0; l < 128; ++l) {
    const float w = sw[l];
    float4 v = *(const float4*)&ib[(size_t)l * DDIM + t * 4];
    acc.x += w * v.x; acc.y += w * v.y; acc.z += w * v.z; acc.w += w * v.w;
  }
  atomicAdd(&o2[b * DDIM + t * 4 + 0], acc.x);
  atomicAdd(&o2[b * DDIM + t * 4 + 1], acc.y);
  atomicAdd(&o2[b * DDIM + t * 4 + 2], acc.z);
  atomicAdd(&o2[b * DDIM + t * 4 + 3], acc.w);
}

// ---------------- GEMM2: o1 = P @ V, fused vectorized epilogue ----------------
__global__ __launch_bounds__(256, 4) void gemm2_kernel(
    const _Float16* __restrict__ Pm, const _Float16* __restrict__ Vt,
    const float* __restrict__ input, const float* __restrict__ o2,
    float* __restrict__ out) {
  const int id = blockIdx.x;                  // nwg = 2048
  const int wg = (id & 7) * 256 + (id >> 3);
  const int b = wg >> 7, rem = wg & 127, by = rem >> 3, bx = rem & 7;
  const int t = threadIdx.x, lane = t & 63, wid = t >> 6;
  const int wr = wid >> 1, wc = wid & 1;
  __shared__ union SM2 {
    struct { _Float16 a[128 * 64]; _Float16 b[128 * 64]; } ab;
    float c[16 * 132];                        // padded C-panel stage
  } sm;
  const _Float16* Ab = Pm + ((size_t)b * LDIM + by * 128) * MDIM;
  const _Float16* Bb = Vt + ((size_t)b * DDIM + bx * 128) * MDIM;
  f32x4v acc[4][4];
#pragma unroll
  for (int i = 0; i < 4; ++i)
#pragma unroll
    for (int j = 0; j < 4; ++j) acc[i][j] = (f32x4v){0.f, 0.f, 0.f, 0.f};

  for (int ks = 0; ks < MDIM / 64; ++ks) {
    __syncthreads();
    stage128(Ab, Bb, sm.ab.a, sm.ab.b, MDIM, ks * 64, wid, lane);
    __syncthreads();
    compute128(sm.ab.a, sm.ab.b, acc, wr, wc, lane);
  }

  // epilogue: 8 panels of 16 rows x 128 cols, staged f32 in LDS, float4 nt out
  const int cq = (t & 15) * 4;
  const float4 o2a = *(const float4*)&o2[b * DDIM + bx * 128 + cq];
  const float4 o2b = *(const float4*)&o2[b * DDIM + bx * 128 + 64 + cq];
  const int r16 = t >> 4;
  __syncthreads();
#pragma unroll
  for (int pp = 0; pp < 8; ++pp) {
    if (wr == (pp >> 2)) {
      const int pmi = pp & 3;
#pragma unroll
      for (int ni = 0; ni < 4; ++ni)
#pragma unroll
        for (int r = 0; r < 4; ++r)
          sm.c[((lane >> 4) * 4 + r) * 132 + wc * 64 + ni * 16 + (lane & 15)] =
              acc[pmi][ni][r];
    }
    __syncthreads();
    const size_t l = (size_t)by * 128 + pp * 16 + r16;
    const float4 c0 = *(const float4*)&sm.c[r16 * 132 + cq];
    const float4 c1 = *(const float4*)&sm.c[r16 * 132 + 64 + cq];
    const float* ibp = &input[((size_t)b * LDIM + l) * DDIM + bx * 128];
    const float4 i0 = *(const float4*)&ibp[cq];
    const float4 i1 = *(const float4*)&ibp[64 + cq];
    float* ob = &out[((size_t)b * LDIM + l) * (4 * DDIM) + bx * 128];
    nts4(i0, ob + cq);
    nts4(i1, ob + 64 + cq);
    nts4(c0, ob + DDIM + cq);
    nts4(c1, ob + DDIM + 64 + cq);
    nts4(m4(i0, c0), ob + 2 * DDIM + cq);
    nts4(m4(i1, c1), ob + 2 * DDIM + 64 + cq);
    nts4(m4(o2a, c0), ob + 3 * DDIM + cq);
    nts4(m4(o2b, c1), ob + 3 * DDIM + 64 + cq);
    __syncthreads();
  }
}

extern "C" void kernel_launch(void* const* d_in, const int* in_sizes, int n_in,
                              void* d_out, int out_size, void* d_ws, size_t ws_size,
                              hipStream_t stream) {
  (void)in_sizes; (void)n_in; (void)out_size; (void)ws_size;
  const float* input  = (const float*)d_in[0];
  const float* memory = (const float*)d_in[1];
  const int*   mask   = (const int*)d_in[2];
  const float* w_in   = (const float*)d_in[3];
  const float* w_mem  = (const float*)d_in[4];
  const float* scale  = (const float*)d_in[5];
  float* out = (float*)d_out;

  char* p = (char*)d_ws;
  _Float16* Qh = (_Float16*)p; p += (size_t)BDIM * LDIM * DDIM * 2;
  _Float16* Kh = (_Float16*)p; p += (size_t)BDIM * MDIM * DDIM * 2;
  _Float16* Vt = (_Float16*)p; p += (size_t)BDIM * DDIM * MDIM * 2;
  _Float16* Sp = (_Float16*)p; p += (size_t)BDIM * LDIM * MDIM * 2;
  float* idot = (float*)p; p += (size_t)BDIM * LDIM * 4;
  float* mdot = (float*)p; p += (size_t)BDIM * MDIM * 4;
  float* rmax = (float*)p; p += (size_t)BDIM * LDIM * 4;
  float* w2   = (float*)p; p += (size_t)BDIM * LDIM * 4;
  float* o2   = (float*)p; p += (size_t)BDIM * DDIM * 4;

  conv_kernel<<<dim3(BDIM * LDIM / 4), dim3(256), 0, stream>>>(
      input, memory, w_in, w_mem, scale, Qh, Kh, idot, mdot);
  tr_kernel<<<dim3(DDIM / 64, MDIM / 64, BDIM), dim3(256), 0, stream>>>(Kh, Vt);
  gemm1_kernel<<<dim3(BDIM * 16 * 16), dim3(256), 0, stream>>>(
      Qh, Kh, idot, mdot, mask, Sp);
  softmax_rows<<<dim3(BDIM * LDIM / 4), dim3(256), 0, stream>>>(Sp, rmax);
  w2a_kernel<<<dim3(BDIM), dim3(256), 0, stream>>>(rmax, w2, o2);
  o2_kernel<<<dim3(LDIM / 128, BDIM), dim3(256), 0, stream>>>(input, w2, o2);
  gemm2_kernel<<<dim3(BDIM * 16 * 8), dim3(256), 0, stream>>>(
      Sp, Vt, input, o2, out);
}